// Round 3
// baseline (387.781 us; speedup 1.0000x reference)
//
#include <hip/hip_runtime.h>

// SNU with bias-sign collapse:
//   y_t = (relu(xw_t + 0.8*h*(1-y)) + b > 0).  relu >= 0, so b_h > 0  =>  y == 1 for all t.
// Only columns with b_h <= 0 (~81 of 512) need the GEMM + sequential scan.
//
// R11:
//   - Dropped split-K entirely. The output is binary (spike thresholds to {0,1}), so
//     GEMM accumulation order need not match the split-K partial order (verified:
//     R6->R8 order changes kept absmax 0.0). Each gemm block now runs full K=512 with
//     the UNMODIFIED R8 inner loop (129 us known-good; R9/R10 proved both register
//     and global_load_lds double-buffering lose to cross-block TLP here).
//     -> gemm writes 32 MB instead of 128 MB; scan reads 32 MB instead of 128 MB.
//   - scan_fill: same producer-consumer skeleton, but windows grow 16 -> 64 t-steps
//     (single stream now: 64 t x 32 cols = 512 float4 = 1 load/thread/window).
//     Barriers per block: 64 -> 16.
//
// ws layout (bytes):
//   4096    : float Wc[512][256]  gathered W columns (512 KB)
//   1<<20   : float xw[T=512][B=128][128]    full-K GEMM result, (t,b,j), 32 MB
//   40<<20  : float xwc1[T=512][B=128][128]  overflow buffer (j in [128,256)),
//                                            touched only if count > 128 (P ~ 6e-9)

#define DECAYF 0.8f

// ---------- per-block compaction recompute: one wave of ballots ----------
__device__ __forceinline__ int block_compact(const float* __restrict__ bias,
                                             int* idx_s, int* cnt_s) {
    const int tid = threadIdx.x;
    if (tid < 64) {
        int base = 0;
        #pragma unroll
        for (int w = 0; w < 8; w++) {
            bool p = bias[w * 64 + tid] <= 0.0f;
            unsigned long long m = __ballot(p);
            if (p) idx_s[base + __popcll(m & ((1ull << tid) - 1ull))] = w * 64 + tid;
            base += __popcll(m);
        }
        if (tid == 0) cnt_s[0] = base;
    }
    __syncthreads();
    const int total = cnt_s[0];
    const int i0 = (total > 0) ? idx_s[0] : 0;
    for (int j = total + tid; j < 256; j += blockDim.x) idx_s[j] = i0;
    __syncthreads();
    return total;
}

// ---------- 1. gather Wc[i][j] = W[i][idx[j]] ----------
__global__ __launch_bounds__(256) void gather_W(const float* __restrict__ bias,
                                                const float* __restrict__ W,
                                                float* __restrict__ Wc) {
    __shared__ int idx_s[256];
    __shared__ int cnt_s[1];
    block_compact(bias, idx_s, cnt_s);
    const int i = blockIdx.x;            // 512 rows
    const int j = threadIdx.x;           // 256 cols
    Wc[i * 256 + j] = W[i * 512 + idx_s[j]];
}

// ---------- 2. GEMM: x(B,I,T) x Wc(I,:) -> xw, full K, R8 inner loop ----------
// grid (2, 4, 128) = (kc, t-tiles, B).  kc==0: cols 0..127 -> xw.
// kc==1: overflow (cols 128..255) -> xwc1; exits immediately if count <= 128.
__global__ __launch_bounds__(256) void gemm_split(const float* __restrict__ x,
                                                  const float* __restrict__ Wc,
                                                  const float* __restrict__ bias,
                                                  float* __restrict__ xw,
                                                  float* __restrict__ xwc1) {
    const int kc = blockIdx.x;
    const int tid = threadIdx.x;
    int coff;
    float* op;
    if (kc == 0) { coff = 0; op = xw; }
    else {
        __shared__ int cnt_s;
        if (tid < 64) {
            int tot = 0;
            #pragma unroll
            for (int w = 0; w < 8; w++)
                tot += __popcll(__ballot(bias[w * 64 + tid] <= 0.0f));
            if (tid == 0) cnt_s = tot;
        }
        __syncthreads();
        if (cnt_s <= 128) return;
        coff = 128; op = xwc1;
    }
    const int I = 512, T = 512, NC = 256;
    const int b  = blockIdx.z;
    const int t0 = blockIdx.y * 128;

    __shared__ float As[16][132];  // [i][t]
    __shared__ float Bs[16][132];  // [i][j]

    const int wave = tid >> 6;
    const int lane = tid & 63;
    const int lx = lane & 7;
    const int ly = lane >> 3;
    const int m_base = ((wave >> 1) << 6) + ly * 8;  // t within tile (0..127)
    const int n_base = ((wave & 1) << 6) + lx * 8;   // j within 128 cols

    float acc[8][8];
    #pragma unroll
    for (int i = 0; i < 8; i++)
        #pragma unroll
        for (int j = 0; j < 8; j++) acc[i][j] = 0.f;

    const float* xb = x + (size_t)b * I * T;

    for (int k0 = 0; k0 < 512; k0 += 16) {
        #pragma unroll
        for (int j = 0; j < 2; j++) {   // stage 16x128 of A and B: 2 float4/thread each
            int id2 = tid + j * 256;
            int row = id2 >> 5;
            int c4  = (id2 & 31) << 2;
            *(float4*)&As[row][c4] = *(const float4*)(xb + (size_t)(k0 + row) * T + t0 + c4);
            *(float4*)&Bs[row][c4] = *(const float4*)(Wc + (size_t)(k0 + row) * NC + coff + c4);
        }
        __syncthreads();
        #pragma unroll
        for (int kk = 0; kk < 16; kk++) {
            float a[8], bb[8];
            *(float4*)&a[0]  = *(const float4*)&As[kk][m_base];
            *(float4*)&a[4]  = *(const float4*)&As[kk][m_base + 4];
            *(float4*)&bb[0] = *(const float4*)&Bs[kk][n_base];
            *(float4*)&bb[4] = *(const float4*)&Bs[kk][n_base + 4];
            #pragma unroll
            for (int mi = 0; mi < 8; mi++)
                #pragma unroll
                for (int ni = 0; ni < 8; ni++)
                    acc[mi][ni] = fmaf(a[mi], bb[ni], acc[mi][ni]);
        }
        __syncthreads();
    }

    #pragma unroll
    for (int mi = 0; mi < 8; mi++) {
        int t = t0 + m_base + mi;
        float* o = op + ((size_t)t * 128 + b) * 128 + n_base;
        *(float4*)o       = *(float4*)&acc[mi][0];
        *(float4*)(o + 4) = *(float4*)&acc[mi][4];
    }
}

// ---------- 3. scan + fill, one dispatch, 512 threads/block ----------
// blocks [0,512)    : scan role, b = id>>2, jq = id&3 (32 columns each). LDS-windowed
//                     producer-consumer, 64-t windows (1 float4 load/thread/window),
//                     lanes 0..31 run the recurrence. 16 barriers/block.
// blocks [512,1536) : ones-fill for rows with bias > 0.
// blocks [1536,1664): overflow scan (j in [128,count)), only if count > 128.
__global__ __launch_bounds__(512) void scan_fill(const float* __restrict__ xw,
                                                 const float* __restrict__ xwc1,
                                                 const float* __restrict__ bias,
                                                 float* __restrict__ out) {
    const int T = 512;
    const int id  = blockIdx.x;
    const int tid = threadIdx.x;

    if (id >= 512 && id < 1536) {   // ---- fill ----
        const float4 ones = make_float4(1.f, 1.f, 1.f, 1.f);
        float4* out4 = (float4*)out;
        const size_t base = (size_t)(id - 512) * 8192 + tid;
        #pragma unroll
        for (int q = 0; q < 16; q++) {
            size_t f4 = base + (size_t)q * 512;      // 1024*8192 = 8M float4 = out
            int h = (int)((f4 >> 7) & 511);          // (B,H,T): 128 float4 per h-row
            if (bias[h] > 0.0f) out4[f4] = ones;
        }
        return;
    }

    __shared__ int idx_s[256];
    __shared__ int cnt_s[1];
    const int count = block_compact(bias, idx_s, cnt_s);

    if (id >= 1536) {   // ---- overflow scan: j in [128, count), single stream ----
        if (count <= 128) return;
        if (tid >= count - 128) return;
        const int b = id - 1536;
        const int j = 128 + tid;
        const int h = idx_s[j];
        const float bv = bias[h];
        const float* p = xwc1 + (size_t)b * 128 + tid;
        float* o = out + ((size_t)b * 512 + h) * (size_t)T;
        const size_t STR = (size_t)128 * 128;
        float hs = 0.f, y = 0.f;
        float nx[8];
        #pragma unroll
        for (int d = 0; d < 8; d++) nx[d] = p[(size_t)d * STR];
        for (int t0 = 0; t0 < T; t0 += 8) {
            float cur[8], yb[8];
            #pragma unroll
            for (int d = 0; d < 8; d++) cur[d] = nx[d];
            const bool more = (t0 + 8) < T;
            #pragma unroll
            for (int d = 0; d < 8; d++)
                nx[d] = more ? p[(size_t)(t0 + 8 + d) * STR] : 0.f;
            #pragma unroll
            for (int d = 0; d < 8; d++) {
                hs = fmaf(DECAYF * hs, 1.f - y, cur[d]);
                hs = fmaxf(hs, 0.f);
                y  = (hs + bv > 0.f) ? 1.f : 0.f;
                yb[d] = y;
            }
            *(float4*)(o + t0)     = *(float4*)&yb[0];
            *(float4*)(o + t0 + 4) = *(float4*)&yb[4];
        }
        return;
    }

    // ---- main scan: b = id>>2, columns jq*32 .. jq*32+31, 64-t windows ----
    const int b  = id >> 2;
    const int jq = id & 3;
    if (jq * 32 >= count) return;        // uniform per block

    const float4* xw4 = (const float4*)xw;
    // load map: tid -> j4 = tid&7 (float4 within the 32-col slice), toff = tid>>3
    // (t within window, 0..63). Window w, t = w*64 + toff:
    //   src float4 = (w*64 + toff)*4096 + b*32 + jq*8 + j4   (t-stride = 128*128/4)
    const int j4l  = tid & 7;
    const int toff = tid >> 3;
    const size_t src_base = (size_t)b * 32 + jq * 8 + j4l;

    __shared__ float4 win4[2][512];      // [buf][toff*8 + j4]  16 KB
    const float* winf = (const float*)win4;

    // compute-lane state (lanes 0..31)
    const int jl = tid;                   // column within quarter
    const int j  = jq * 32 + jl;
    const bool active = (tid < 32) && (j < count);
    const int h = active ? idx_s[j] : 0;
    const float bv = active ? bias[h] : 0.f;
    float* o = out + ((size_t)b * 512 + h) * (size_t)T;
    float hs = 0.f, y = 0.f;

    // prologue: window 0 into buf 0
    win4[0][tid] = xw4[(size_t)toff * 4096 + src_base];
    __syncthreads();

    for (int w = 0; w < 8; w++) {
        const int buf = w & 1;
        float4 v;
        const bool more = (w + 1) < 8;
        if (more)   // issue next window's load now; consumed after this window's compute
            v = xw4[(size_t)((w + 1) * 64 + toff) * 4096 + src_base];

        if (active) {
            const int t0w = w * 64;
            #pragma unroll
            for (int s = 0; s < 4; s++) {
                float yb[16];
                #pragma unroll
                for (int d = 0; d < 16; d++) {
                    float sv = winf[(size_t)(buf * 512 + (s * 16 + d) * 8) * 4 + jl];
                    // (1-y) is exactly 0 or 1 -> relu chain matches reference rounding
                    hs = fmaf(DECAYF * hs, 1.f - y, sv);
                    hs = fmaxf(hs, 0.f);
                    y  = (hs + bv > 0.f) ? 1.f : 0.f;
                    yb[d] = y;
                }
                const int t0 = t0w + s * 16;
                *(float4*)(o + t0)      = *(float4*)&yb[0];
                *(float4*)(o + t0 + 4)  = *(float4*)&yb[4];
                *(float4*)(o + t0 + 8)  = *(float4*)&yb[8];
                *(float4*)(o + t0 + 12) = *(float4*)&yb[12];
            }
        }
        if (more)
            win4[buf ^ 1][tid] = v;      // writes the buffer NOT being read: safe
        __syncthreads();
    }
}

extern "C" void kernel_launch(void* const* d_in, const int* in_sizes, int n_in,
                              void* d_out, int out_size, void* d_ws, size_t ws_size,
                              hipStream_t stream) {
    const float* x    = (const float*)d_in[0];  // (128, 512, 512)
    const float* W    = (const float*)d_in[1];  // (512, 512)
    const float* bias = (const float*)d_in[2];  // (1, 512)
    float* out = (float*)d_out;                 // (B,H,T) = (128, 512, 512)

    char* ws = (char*)d_ws;
    float* Wc   = (float*)(ws + 4096);
    float* xw   = (float*)(ws + ((size_t)1 << 20));
    float* xwc1 = (float*)(ws + ((size_t)40 << 20));

    gather_W<<<512, 256, 0, stream>>>(bias, W, Wc);
    dim3 g1(2, 4, 128);   // (main + overflow, t-tiles, B)
    gemm_split<<<g1, 256, 0, stream>>>(x, Wc, bias, xw, xwc1);
    scan_fill<<<1664, 512, 0, stream>>>(xw, xwc1, bias, out);
}

// Round 4
// 376.761 us; speedup vs baseline: 1.0292x; 1.0292x over previous
//
#include <hip/hip_runtime.h>

// SNU with bias-sign collapse:
//   y_t = (relu(xw_t + 0.8*h*(1-y)) + b > 0).  relu >= 0, so b_h > 0  =>  y == 1 for all t.
// Only columns with b_h <= 0 (~81 of 512) need the GEMM + sequential scan.
//
// R12:
//   - Full-K GEMM kept (32 MB write), but t-tile halved 128 -> 64: grid (2,8,128)
//     = 1024 working blocks = 4 blocks/CU = 16 waves/CU. R9/R10/R11 proved this
//     GEMM hides latency purely via cross-block TLP (VALUBusy tracks resident
//     waves: 53% @ ~2.6 blk/CU, 30% @ 2 blk/CU). Per-thread tile 4(t) x 8(j),
//     B-fragment split j = {tn*4} u {64+tn*4} keeps LDS reads 16B-stride ->
//     conflict-free (tn*8 mapping would 4-way conflict).
//   - K-order sequential 0..511 per element: bit-identical to R11 (absmax 0.0).
//   - scan_fill unchanged from R11.
//
// ws layout (bytes):
//   4096    : float Wc[512][256]  gathered W columns (512 KB)
//   1<<20   : float xw[T=512][B=128][128]    full-K GEMM result, (t,b,j), 32 MB
//   40<<20  : float xwc1[T=512][B=128][128]  overflow buffer (j in [128,256)),
//                                            touched only if count > 128 (P ~ 6e-9)

#define DECAYF 0.8f

// ---------- per-block compaction recompute: one wave of ballots ----------
__device__ __forceinline__ int block_compact(const float* __restrict__ bias,
                                             int* idx_s, int* cnt_s) {
    const int tid = threadIdx.x;
    if (tid < 64) {
        int base = 0;
        #pragma unroll
        for (int w = 0; w < 8; w++) {
            bool p = bias[w * 64 + tid] <= 0.0f;
            unsigned long long m = __ballot(p);
            if (p) idx_s[base + __popcll(m & ((1ull << tid) - 1ull))] = w * 64 + tid;
            base += __popcll(m);
        }
        if (tid == 0) cnt_s[0] = base;
    }
    __syncthreads();
    const int total = cnt_s[0];
    const int i0 = (total > 0) ? idx_s[0] : 0;
    for (int j = total + tid; j < 256; j += blockDim.x) idx_s[j] = i0;
    __syncthreads();
    return total;
}

// ---------- 1. gather Wc[i][j] = W[i][idx[j]] ----------
__global__ __launch_bounds__(256) void gather_W(const float* __restrict__ bias,
                                                const float* __restrict__ W,
                                                float* __restrict__ Wc) {
    __shared__ int idx_s[256];
    __shared__ int cnt_s[1];
    block_compact(bias, idx_s, cnt_s);
    const int i = blockIdx.x;            // 512 rows
    const int j = threadIdx.x;           // 256 cols
    Wc[i * 256 + j] = W[i * 512 + idx_s[j]];
}

// ---------- 2. GEMM: x(B,I,T) x Wc(I,:) -> xw, full K, 64x128 tile ----------
// grid (2, 8, 128) = (kc, t-tiles, B).  kc==0: cols 0..127 -> xw.
// kc==1: overflow (cols 128..255) -> xwc1; exits immediately if count <= 128.
__global__ __launch_bounds__(256) void gemm_split(const float* __restrict__ x,
                                                  const float* __restrict__ Wc,
                                                  const float* __restrict__ bias,
                                                  float* __restrict__ xw,
                                                  float* __restrict__ xwc1) {
    const int kc = blockIdx.x;
    const int tid = threadIdx.x;
    int coff;
    float* op;
    if (kc == 0) { coff = 0; op = xw; }
    else {
        __shared__ int cnt_s;
        if (tid < 64) {
            int tot = 0;
            #pragma unroll
            for (int w = 0; w < 8; w++)
                tot += __popcll(__ballot(bias[w * 64 + tid] <= 0.0f));
            if (tid == 0) cnt_s = tot;
        }
        __syncthreads();
        if (cnt_s <= 128) return;
        coff = 128; op = xwc1;
    }
    const int I = 512, T = 512, NC = 256;
    const int b  = blockIdx.z;
    const int t0 = blockIdx.y * 64;

    __shared__ float As[16][68];   // [i][t]  64-wide tile + pad
    __shared__ float Bs[16][132];  // [i][j]  128-wide + pad

    const int tm = tid >> 4;       // 0..15 -> t = t0 + tm*4 + (0..3)
    const int tn = tid & 15;       // 0..15 -> j = tn*4 + (0..3)  and  64 + tn*4 + (0..3)

    float acc[4][8];
    #pragma unroll
    for (int i = 0; i < 4; i++)
        #pragma unroll
        for (int j = 0; j < 8; j++) acc[i][j] = 0.f;

    const float* xb = x + (size_t)b * I * T;

    // staging maps:
    //   A: 16 rows x 64 floats = 256 float4, 1/thread: row = tid>>4, cf = (tid&15)*4
    //   B: 16 rows x 128 floats = 512 float4, 2/thread (verbatim R8 map)
    const int ar = tid >> 4;
    const int ac = (tid & 15) << 2;

    for (int k0 = 0; k0 < 512; k0 += 16) {
        *(float4*)&As[ar][ac] = *(const float4*)(xb + (size_t)(k0 + ar) * T + t0 + ac);
        #pragma unroll
        for (int j = 0; j < 2; j++) {
            int id2 = tid + j * 256;
            int row = id2 >> 5;
            int c4  = (id2 & 31) << 2;
            *(float4*)&Bs[row][c4] = *(const float4*)(Wc + (size_t)(k0 + row) * NC + coff + c4);
        }
        __syncthreads();
        #pragma unroll
        for (int kk = 0; kk < 16; kk++) {
            float a[4], bb[8];
            *(float4*)&a[0]  = *(const float4*)&As[kk][tm * 4];
            *(float4*)&bb[0] = *(const float4*)&Bs[kk][tn * 4];
            *(float4*)&bb[4] = *(const float4*)&Bs[kk][64 + tn * 4];
            #pragma unroll
            for (int mi = 0; mi < 4; mi++)
                #pragma unroll
                for (int ni = 0; ni < 8; ni++)
                    acc[mi][ni] = fmaf(a[mi], bb[ni], acc[mi][ni]);
        }
        __syncthreads();
    }

    #pragma unroll
    for (int mi = 0; mi < 4; mi++) {
        int t = t0 + tm * 4 + mi;
        float* o = op + ((size_t)t * 128 + b) * 128;
        *(float4*)(o + tn * 4)      = *(float4*)&acc[mi][0];
        *(float4*)(o + 64 + tn * 4) = *(float4*)&acc[mi][4];
    }
}

// ---------- 3. scan + fill, one dispatch, 512 threads/block ----------
// blocks [0,512)    : scan role, b = id>>2, jq = id&3 (32 columns each). LDS-windowed
//                     producer-consumer, 64-t windows (1 float4 load/thread/window),
//                     lanes 0..31 run the recurrence. 16 barriers/block.
// blocks [512,1536) : ones-fill for rows with bias > 0.
// blocks [1536,1664): overflow scan (j in [128,count)), only if count > 128.
__global__ __launch_bounds__(512) void scan_fill(const float* __restrict__ xw,
                                                 const float* __restrict__ xwc1,
                                                 const float* __restrict__ bias,
                                                 float* __restrict__ out) {
    const int T = 512;
    const int id  = blockIdx.x;
    const int tid = threadIdx.x;

    if (id >= 512 && id < 1536) {   // ---- fill ----
        const float4 ones = make_float4(1.f, 1.f, 1.f, 1.f);
        float4* out4 = (float4*)out;
        const size_t base = (size_t)(id - 512) * 8192 + tid;
        #pragma unroll
        for (int q = 0; q < 16; q++) {
            size_t f4 = base + (size_t)q * 512;      // 1024*8192 = 8M float4 = out
            int h = (int)((f4 >> 7) & 511);          // (B,H,T): 128 float4 per h-row
            if (bias[h] > 0.0f) out4[f4] = ones;
        }
        return;
    }

    __shared__ int idx_s[256];
    __shared__ int cnt_s[1];
    const int count = block_compact(bias, idx_s, cnt_s);

    if (id >= 1536) {   // ---- overflow scan: j in [128, count), single stream ----
        if (count <= 128) return;
        if (tid >= count - 128) return;
        const int b = id - 1536;
        const int j = 128 + tid;
        const int h = idx_s[j];
        const float bv = bias[h];
        const float* p = xwc1 + (size_t)b * 128 + tid;
        float* o = out + ((size_t)b * 512 + h) * (size_t)T;
        const size_t STR = (size_t)128 * 128;
        float hs = 0.f, y = 0.f;
        float nx[8];
        #pragma unroll
        for (int d = 0; d < 8; d++) nx[d] = p[(size_t)d * STR];
        for (int t0 = 0; t0 < T; t0 += 8) {
            float cur[8], yb[8];
            #pragma unroll
            for (int d = 0; d < 8; d++) cur[d] = nx[d];
            const bool more = (t0 + 8) < T;
            #pragma unroll
            for (int d = 0; d < 8; d++)
                nx[d] = more ? p[(size_t)(t0 + 8 + d) * STR] : 0.f;
            #pragma unroll
            for (int d = 0; d < 8; d++) {
                hs = fmaf(DECAYF * hs, 1.f - y, cur[d]);
                hs = fmaxf(hs, 0.f);
                y  = (hs + bv > 0.f) ? 1.f : 0.f;
                yb[d] = y;
            }
            *(float4*)(o + t0)     = *(float4*)&yb[0];
            *(float4*)(o + t0 + 4) = *(float4*)&yb[4];
        }
        return;
    }

    // ---- main scan: b = id>>2, columns jq*32 .. jq*32+31, 64-t windows ----
    const int b  = id >> 2;
    const int jq = id & 3;
    if (jq * 32 >= count) return;        // uniform per block

    const float4* xw4 = (const float4*)xw;
    // load map: tid -> j4 = tid&7 (float4 within the 32-col slice), toff = tid>>3
    // (t within window, 0..63). Window w, t = w*64 + toff:
    //   src float4 = (w*64 + toff)*4096 + b*32 + jq*8 + j4   (t-stride = 128*128/4)
    const int j4l  = tid & 7;
    const int toff = tid >> 3;
    const size_t src_base = (size_t)b * 32 + jq * 8 + j4l;

    __shared__ float4 win4[2][512];      // [buf][toff*8 + j4]  16 KB
    const float* winf = (const float*)win4;

    // compute-lane state (lanes 0..31)
    const int jl = tid;                   // column within quarter
    const int j  = jq * 32 + jl;
    const bool active = (tid < 32) && (j < count);
    const int h = active ? idx_s[j] : 0;
    const float bv = active ? bias[h] : 0.f;
    float* o = out + ((size_t)b * 512 + h) * (size_t)T;
    float hs = 0.f, y = 0.f;

    // prologue: window 0 into buf 0
    win4[0][tid] = xw4[(size_t)toff * 4096 + src_base];
    __syncthreads();

    for (int w = 0; w < 8; w++) {
        const int buf = w & 1;
        float4 v;
        const bool more = (w + 1) < 8;
        if (more)   // issue next window's load now; consumed after this window's compute
            v = xw4[(size_t)((w + 1) * 64 + toff) * 4096 + src_base];

        if (active) {
            const int t0w = w * 64;
            #pragma unroll
            for (int s = 0; s < 4; s++) {
                float yb[16];
                #pragma unroll
                for (int d = 0; d < 16; d++) {
                    float sv = winf[(size_t)(buf * 512 + (s * 16 + d) * 8) * 4 + jl];
                    // (1-y) is exactly 0 or 1 -> relu chain matches reference rounding
                    hs = fmaf(DECAYF * hs, 1.f - y, sv);
                    hs = fmaxf(hs, 0.f);
                    y  = (hs + bv > 0.f) ? 1.f : 0.f;
                    yb[d] = y;
                }
                const int t0 = t0w + s * 16;
                *(float4*)(o + t0)      = *(float4*)&yb[0];
                *(float4*)(o + t0 + 4)  = *(float4*)&yb[4];
                *(float4*)(o + t0 + 8)  = *(float4*)&yb[8];
                *(float4*)(o + t0 + 12) = *(float4*)&yb[12];
            }
        }
        if (more)
            win4[buf ^ 1][tid] = v;      // writes the buffer NOT being read: safe
        __syncthreads();
    }
}

extern "C" void kernel_launch(void* const* d_in, const int* in_sizes, int n_in,
                              void* d_out, int out_size, void* d_ws, size_t ws_size,
                              hipStream_t stream) {
    const float* x    = (const float*)d_in[0];  // (128, 512, 512)
    const float* W    = (const float*)d_in[1];  // (512, 512)
    const float* bias = (const float*)d_in[2];  // (1, 512)
    float* out = (float*)d_out;                 // (B,H,T) = (128, 512, 512)

    char* ws = (char*)d_ws;
    float* Wc   = (float*)(ws + 4096);
    float* xw   = (float*)(ws + ((size_t)1 << 20));
    float* xwc1 = (float*)(ws + ((size_t)40 << 20));

    gather_W<<<512, 256, 0, stream>>>(bias, W, Wc);
    dim3 g1(2, 8, 128);   // (main + overflow, t-tiles, B)
    gemm_split<<<g1, 256, 0, stream>>>(x, Wc, bias, xw, xwc1);
    scan_fill<<<1664, 512, 0, stream>>>(xw, xwc1, bias, out);
}

// Round 5
// 342.657 us; speedup vs baseline: 1.1317x; 1.0995x over previous
//
#include <hip/hip_runtime.h>

// SNU with bias-sign collapse:
//   y_t = (relu(xw_t + 0.8*h*(1-y)) + b > 0).  relu >= 0, so b_h > 0  =>  y == 1 for all t.
// Only columns with b_h <= 0 (~81 of 512) need the GEMM + sequential scan.
//
// R13:
//   - gemm: R8's split-K=4 / 128x128 tile / 8x8 thread-tile structure (129 us
//     proven), but BK 16 -> 32: 4 staging rounds per block instead of 8, 2x the
//     FMA work per barrier round. R12 disproved the TLP theory (2x blocks, same
//     31% VALU); the stall is per-round, so fewer+fatter rounds attack it.
//     K-order per element unchanged (sequential within kc chunk) -> bit-exact.
//   - scan: R8's 4-partial LDS-window producer-consumer, windows 16 -> 32 t-steps
//     (2 loads/thread/window, 17 barriers vs 33). Sum (p0+p1)+(p2+p3) preserved.
//
// ws layout (bytes):
//   4096    : float Wc[512][256]  gathered W columns (512 KB)
//   1<<20   : float xwp[4][T=512][B=128][128]  4 x 32 MB split-K partials, (t,b,j)
//   129<<20 : float xwc1[T=512][B=128][128]    overflow direct buffer (j in [128,256)),
//                                              touched only if count > 128 (P ~ 6e-9)

#define DECAYF 0.8f
#define PART   ((size_t)512 * 128 * 128)   // floats per split-K partial
#define PARTF4 (PART / 4)                  // float4s per partial

// ---------- per-block compaction recompute: one wave of ballots ----------
__device__ __forceinline__ int block_compact(const float* __restrict__ bias,
                                             int* idx_s, int* cnt_s) {
    const int tid = threadIdx.x;
    if (tid < 64) {
        int base = 0;
        #pragma unroll
        for (int w = 0; w < 8; w++) {
            bool p = bias[w * 64 + tid] <= 0.0f;
            unsigned long long m = __ballot(p);
            if (p) idx_s[base + __popcll(m & ((1ull << tid) - 1ull))] = w * 64 + tid;
            base += __popcll(m);
        }
        if (tid == 0) cnt_s[0] = base;
    }
    __syncthreads();
    const int total = cnt_s[0];
    const int i0 = (total > 0) ? idx_s[0] : 0;
    for (int j = total + tid; j < 256; j += blockDim.x) idx_s[j] = i0;
    __syncthreads();
    return total;
}

// ---------- 1. gather Wc[i][j] = W[i][idx[j]] ----------
__global__ __launch_bounds__(256) void gather_W(const float* __restrict__ bias,
                                                const float* __restrict__ W,
                                                float* __restrict__ Wc) {
    __shared__ int idx_s[256];
    __shared__ int cnt_s[1];
    block_compact(bias, idx_s, cnt_s);
    const int i = blockIdx.x;            // 512 rows
    const int j = threadIdx.x;           // 256 cols
    Wc[i * 256 + j] = W[i * 512 + idx_s[j]];
}

// ---------- 2. GEMM: x(B,I,T) x Wc(I,:) -> partials, BK=32 rounds ----------
// grid (5, 4, 128) = (kc, t-tiles, B).  kc<4: split-K chunk of 128 over cols 0..127
// into xwp[kc] (4 rounds of 32). kc==4: overflow (full K, cols 128..255) -> xwc1;
// exits if count<=128.  FMA order per element identical to R8.
__global__ __launch_bounds__(256) void gemm_split(const float* __restrict__ x,
                                                  const float* __restrict__ Wc,
                                                  const float* __restrict__ bias,
                                                  float* __restrict__ xwp,
                                                  float* __restrict__ xwc1) {
    const int kc = blockIdx.x;
    const int tid = threadIdx.x;
    int kbeg, kend, coff;
    float* op;
    if (kc < 4) { kbeg = kc * 128; kend = kbeg + 128; coff = 0;   op = xwp + (size_t)kc * PART; }
    else {
        __shared__ int cnt_s;
        if (tid < 64) {
            int tot = 0;
            #pragma unroll
            for (int w = 0; w < 8; w++)
                tot += __popcll(__ballot(bias[w * 64 + tid] <= 0.0f));
            if (tid == 0) cnt_s = tot;
        }
        __syncthreads();
        if (cnt_s <= 128) return;
        kbeg = 0; kend = 512; coff = 128; op = xwc1;
    }
    const int I = 512, T = 512, NC = 256;
    const int b  = blockIdx.z;
    const int t0 = blockIdx.y * 128;

    __shared__ float As[32][132];  // [i][t]
    __shared__ float Bs[32][132];  // [i][j]

    const int wave = tid >> 6;
    const int lane = tid & 63;
    const int lx = lane & 7;
    const int ly = lane >> 3;
    const int m_base = ((wave >> 1) << 6) + ly * 8;  // t within tile (0..127)
    const int n_base = ((wave & 1) << 6) + lx * 8;   // j within 128 cols

    float acc[8][8];
    #pragma unroll
    for (int i = 0; i < 8; i++)
        #pragma unroll
        for (int j = 0; j < 8; j++) acc[i][j] = 0.f;

    const float* xb = x + (size_t)b * I * T;

    for (int k0 = kbeg; k0 < kend; k0 += 32) {
        #pragma unroll
        for (int q = 0; q < 4; q++) {   // stage 32x128 of A and B: 4 float4/thread each
            int id2 = tid + q * 256;
            int row = id2 >> 5;             // 0..31
            int c4  = (id2 & 31) << 2;
            *(float4*)&As[row][c4] = *(const float4*)(xb + (size_t)(k0 + row) * T + t0 + c4);
            *(float4*)&Bs[row][c4] = *(const float4*)(Wc + (size_t)(k0 + row) * NC + coff + c4);
        }
        __syncthreads();
        #pragma unroll
        for (int kk = 0; kk < 32; kk++) {
            float a[8], bb[8];
            *(float4*)&a[0]  = *(const float4*)&As[kk][m_base];
            *(float4*)&a[4]  = *(const float4*)&As[kk][m_base + 4];
            *(float4*)&bb[0] = *(const float4*)&Bs[kk][n_base];
            *(float4*)&bb[4] = *(const float4*)&Bs[kk][n_base + 4];
            #pragma unroll
            for (int mi = 0; mi < 8; mi++)
                #pragma unroll
                for (int ni = 0; ni < 8; ni++)
                    acc[mi][ni] = fmaf(a[mi], bb[ni], acc[mi][ni]);
        }
        __syncthreads();
    }

    #pragma unroll
    for (int mi = 0; mi < 8; mi++) {
        int t = t0 + m_base + mi;
        float* o = op + ((size_t)t * 128 + b) * 128 + n_base;
        *(float4*)o       = *(float4*)&acc[mi][0];
        *(float4*)(o + 4) = *(float4*)&acc[mi][4];
    }
}

// ---------- 3. scan + reduce + fill, one dispatch, 512 threads/block ----------
// blocks [0,512)    : scan role, b = id>>2, jq = id&3 (32 columns each). LDS-windowed
//                     producer-consumer, 32-t windows (2 float4 loads/thread/window,
//                     double-buffered); lanes 0..31 run the recurrence, summing
//                     (p0+p1)+(p2+p3) = bit-identical to R8's reduce4.
// blocks [512,1536) : ones-fill for rows with bias > 0.
// blocks [1536,1664): overflow scan (j in [128,count)), only if count > 128.
__global__ __launch_bounds__(512) void scan_fill(const float* __restrict__ xwp,
                                                 const float* __restrict__ xwc1,
                                                 const float* __restrict__ bias,
                                                 float* __restrict__ out) {
    const int T = 512;
    const int id  = blockIdx.x;
    const int tid = threadIdx.x;

    if (id >= 512 && id < 1536) {   // ---- fill ----
        const float4 ones = make_float4(1.f, 1.f, 1.f, 1.f);
        float4* out4 = (float4*)out;
        const size_t base = (size_t)(id - 512) * 8192 + tid;
        #pragma unroll
        for (int q = 0; q < 16; q++) {
            size_t f4 = base + (size_t)q * 512;      // 1024*8192 = 8M float4 = out
            int h = (int)((f4 >> 7) & 511);          // (B,H,T): 128 float4 per h-row
            if (bias[h] > 0.0f) out4[f4] = ones;
        }
        return;
    }

    __shared__ int idx_s[256];
    __shared__ int cnt_s[1];
    __shared__ float4 win[2][32][4][8];   // [buf][t_off][partial][j4]  32 KB
    const int count = block_compact(bias, idx_s, cnt_s);

    if (id >= 1536) {   // ---- overflow scan: j in [128, count), single stream ----
        if (count <= 128) return;
        if (tid >= count - 128) return;
        const int b = id - 1536;
        const int j = 128 + tid;
        const int h = idx_s[j];
        const float bv = bias[h];
        const float* p = xwc1 + (size_t)b * 128 + tid;
        float* o = out + ((size_t)b * 512 + h) * (size_t)T;
        const size_t STR = (size_t)128 * 128;
        float hs = 0.f, y = 0.f;
        float nx[8];
        #pragma unroll
        for (int d = 0; d < 8; d++) nx[d] = p[(size_t)d * STR];
        for (int t0 = 0; t0 < T; t0 += 8) {
            float cur[8], yb[8];
            #pragma unroll
            for (int d = 0; d < 8; d++) cur[d] = nx[d];
            const bool more = (t0 + 8) < T;
            #pragma unroll
            for (int d = 0; d < 8; d++)
                nx[d] = more ? p[(size_t)(t0 + 8 + d) * STR] : 0.f;
            #pragma unroll
            for (int d = 0; d < 8; d++) {
                hs = fmaf(DECAYF * hs, 1.f - y, cur[d]);
                hs = fmaxf(hs, 0.f);
                y  = (hs + bv > 0.f) ? 1.f : 0.f;
                yb[d] = y;
            }
            *(float4*)(o + t0)     = *(float4*)&yb[0];
            *(float4*)(o + t0 + 4) = *(float4*)&yb[4];
        }
        return;
    }

    // ---- main scan: b = id>>2, columns jq*32 .. jq*32+31, 32-t windows ----
    const int b  = id >> 2;
    const int jq = id & 3;
    if (jq * 32 >= count) return;        // uniform per block

    const float4* xwp4 = (const float4*)xwp;
    // load map (x2 per window): f = tid: j4 = f&7, p = (f>>3)&3, t_off = f>>5 (0..15)
    // and t_off+16.  src float4 = p*PARTF4 + t*4096 + b*32 + jq*8 + j4.
    const int j4l  = tid & 7;
    const int pp   = (tid >> 3) & 3;
    const int toff = tid >> 5;
    const size_t src_base = (size_t)pp * PARTF4 + (size_t)b * 32 + jq * 8 + j4l;

    // compute-lane state (lanes 0..31)
    const int jl = tid;                   // column within quarter
    const int j  = jq * 32 + jl;
    const bool active = (tid < 32) && (j < count);
    const int h = active ? idx_s[j] : 0;
    const float bv = active ? bias[h] : 0.f;
    float* o = out + ((size_t)b * 512 + h) * (size_t)T;
    float hs = 0.f, y = 0.f;

    const float* winf = (const float*)win;

    // prologue: window 0 into buf 0
    {
        win[0][toff     ][pp][j4l] = xwp4[src_base + (size_t)(toff     ) * 4096];
        win[0][toff + 16][pp][j4l] = xwp4[src_base + (size_t)(toff + 16) * 4096];
    }
    __syncthreads();

    for (int w = 0; w < 16; w++) {
        const int buf = w & 1;
        float4 v0, v1;
        const bool more = (w + 1) < 16;
        if (more) {  // issue next window's loads now; consumed at the ds_writes below
            v0 = xwp4[src_base + (size_t)((w + 1) * 32 + toff     ) * 4096];
            v1 = xwp4[src_base + (size_t)((w + 1) * 32 + toff + 16) * 4096];
        }

        if (active) {
            const int t0w = w * 32;
            #pragma unroll
            for (int s = 0; s < 2; s++) {
                float yb[16];
                #pragma unroll
                for (int d = 0; d < 16; d++) {
                    const int rb = ((buf * 32 + s * 16 + d) * 4) * 32 + jl;
                    float sv = (winf[rb] + winf[rb + 32]) + (winf[rb + 64] + winf[rb + 96]);
                    // (1-y) is exactly 0 or 1 -> relu chain matches reference rounding
                    hs = fmaf(DECAYF * hs, 1.f - y, sv);
                    hs = fmaxf(hs, 0.f);
                    y  = (hs + bv > 0.f) ? 1.f : 0.f;
                    yb[d] = y;
                }
                const int t0 = t0w + s * 16;
                *(float4*)(o + t0)      = *(float4*)&yb[0];
                *(float4*)(o + t0 + 4)  = *(float4*)&yb[4];
                *(float4*)(o + t0 + 8)  = *(float4*)&yb[8];
                *(float4*)(o + t0 + 12) = *(float4*)&yb[12];
            }
        }
        if (more) {
            win[buf ^ 1][toff     ][pp][j4l] = v0;   // writes buffer NOT being read
            win[buf ^ 1][toff + 16][pp][j4l] = v1;
        }
        __syncthreads();
    }
}

extern "C" void kernel_launch(void* const* d_in, const int* in_sizes, int n_in,
                              void* d_out, int out_size, void* d_ws, size_t ws_size,
                              hipStream_t stream) {
    const float* x    = (const float*)d_in[0];  // (128, 512, 512)
    const float* W    = (const float*)d_in[1];  // (512, 512)
    const float* bias = (const float*)d_in[2];  // (1, 512)
    float* out = (float*)d_out;                 // (B,H,T) = (128, 512, 512)

    char* ws = (char*)d_ws;
    float* Wc   = (float*)(ws + 4096);
    float* xwp  = (float*)(ws + ((size_t)1 << 20));
    float* xwc1 = (float*)(ws + ((size_t)129 << 20));

    gather_W<<<512, 256, 0, stream>>>(bias, W, Wc);
    dim3 g1(5, 4, 128);   // (4 kc + overflow, t-tiles, B)
    gemm_split<<<g1, 256, 0, stream>>>(x, Wc, bias, xwp, xwc1);
    scan_fill<<<1664, 512, 0, stream>>>(xwp, xwc1, bias, out);
}

// Round 6
// 342.026 us; speedup vs baseline: 1.1338x; 1.0018x over previous
//
#include <hip/hip_runtime.h>

// SNU with bias-sign collapse:
//   y_t = (relu(xw_t + 0.8*h*(1-y)) + b > 0).  relu >= 0, so b_h > 0  =>  y == 1 for all t.
// Only columns with b_h <= 0 (~81 of 512) need the GEMM + sequential scan.
//
// R14:
//   - Split-K 4 -> 2 (K-chunks of 256). Keeps 1024 working gemm blocks (4/CU, one
//     full residency round) with R13's proven BK=32 round structure, but halves
//     partial traffic: gemm writes 64 MB (was 128), scan reads 64 MB and sums
//     (p0+p1) with one add (was 3). Same total rounds: 1024x8 = 2048x4.
//   - scan windows 32 -> 64 t-steps (2 partials x 64 t x 8 j4 = 2 loads/thread,
//     9 barriers vs 17, same 32 KB LDS dbuf).
//   - Sum-order regrouping (256-K chunks) is the same class of change verified
//     harmless in R6->R8->R11 (binary output, absmax 0.0 throughout).
//
// ws layout (bytes):
//   4096    : float Wc[512][256]  gathered W columns (512 KB)
//   1<<20   : float xwp[2][T=512][B=128][128]  2 x 32 MB split-K partials, (t,b,j)
//   80<<20  : float xwc1[T=512][B=128][128]    overflow direct buffer (j in [128,256)),
//                                              touched only if count > 128 (P ~ 6e-9)

#define DECAYF 0.8f
#define PART   ((size_t)512 * 128 * 128)   // floats per split-K partial
#define PARTF4 (PART / 4)                  // float4s per partial

// ---------- per-block compaction recompute: one wave of ballots ----------
__device__ __forceinline__ int block_compact(const float* __restrict__ bias,
                                             int* idx_s, int* cnt_s) {
    const int tid = threadIdx.x;
    if (tid < 64) {
        int base = 0;
        #pragma unroll
        for (int w = 0; w < 8; w++) {
            bool p = bias[w * 64 + tid] <= 0.0f;
            unsigned long long m = __ballot(p);
            if (p) idx_s[base + __popcll(m & ((1ull << tid) - 1ull))] = w * 64 + tid;
            base += __popcll(m);
        }
        if (tid == 0) cnt_s[0] = base;
    }
    __syncthreads();
    const int total = cnt_s[0];
    const int i0 = (total > 0) ? idx_s[0] : 0;
    for (int j = total + tid; j < 256; j += blockDim.x) idx_s[j] = i0;
    __syncthreads();
    return total;
}

// ---------- 1. gather Wc[i][j] = W[i][idx[j]] ----------
__global__ __launch_bounds__(256) void gather_W(const float* __restrict__ bias,
                                                const float* __restrict__ W,
                                                float* __restrict__ Wc) {
    __shared__ int idx_s[256];
    __shared__ int cnt_s[1];
    block_compact(bias, idx_s, cnt_s);
    const int i = blockIdx.x;            // 512 rows
    const int j = threadIdx.x;           // 256 cols
    Wc[i * 256 + j] = W[i * 512 + idx_s[j]];
}

// ---------- 2. GEMM: x(B,I,T) x Wc(I,:) -> partials, split-K=2, BK=32 ----------
// grid (3, 4, 128) = (kc, t-tiles, B).  kc<2: K-chunk of 256 over cols 0..127
// into xwp[kc] (8 rounds of 32). kc==2: overflow (full K, cols 128..255) -> xwc1;
// exits if count<=128.  FMA order per element sequential within its K-chunk.
__global__ __launch_bounds__(256) void gemm_split(const float* __restrict__ x,
                                                  const float* __restrict__ Wc,
                                                  const float* __restrict__ bias,
                                                  float* __restrict__ xwp,
                                                  float* __restrict__ xwc1) {
    const int kc = blockIdx.x;
    const int tid = threadIdx.x;
    int kbeg, kend, coff;
    float* op;
    if (kc < 2) { kbeg = kc * 256; kend = kbeg + 256; coff = 0;   op = xwp + (size_t)kc * PART; }
    else {
        __shared__ int cnt_s;
        if (tid < 64) {
            int tot = 0;
            #pragma unroll
            for (int w = 0; w < 8; w++)
                tot += __popcll(__ballot(bias[w * 64 + tid] <= 0.0f));
            if (tid == 0) cnt_s = tot;
        }
        __syncthreads();
        if (cnt_s <= 128) return;
        kbeg = 0; kend = 512; coff = 128; op = xwc1;
    }
    const int I = 512, T = 512, NC = 256;
    const int b  = blockIdx.z;
    const int t0 = blockIdx.y * 128;

    __shared__ float As[32][132];  // [i][t]
    __shared__ float Bs[32][132];  // [i][j]

    const int wave = tid >> 6;
    const int lane = tid & 63;
    const int lx = lane & 7;
    const int ly = lane >> 3;
    const int m_base = ((wave >> 1) << 6) + ly * 8;  // t within tile (0..127)
    const int n_base = ((wave & 1) << 6) + lx * 8;   // j within 128 cols

    float acc[8][8];
    #pragma unroll
    for (int i = 0; i < 8; i++)
        #pragma unroll
        for (int j = 0; j < 8; j++) acc[i][j] = 0.f;

    const float* xb = x + (size_t)b * I * T;

    for (int k0 = kbeg; k0 < kend; k0 += 32) {
        #pragma unroll
        for (int q = 0; q < 4; q++) {   // stage 32x128 of A and B: 4 float4/thread each
            int id2 = tid + q * 256;
            int row = id2 >> 5;             // 0..31
            int c4  = (id2 & 31) << 2;
            *(float4*)&As[row][c4] = *(const float4*)(xb + (size_t)(k0 + row) * T + t0 + c4);
            *(float4*)&Bs[row][c4] = *(const float4*)(Wc + (size_t)(k0 + row) * NC + coff + c4);
        }
        __syncthreads();
        #pragma unroll
        for (int kk = 0; kk < 32; kk++) {
            float a[8], bb[8];
            *(float4*)&a[0]  = *(const float4*)&As[kk][m_base];
            *(float4*)&a[4]  = *(const float4*)&As[kk][m_base + 4];
            *(float4*)&bb[0] = *(const float4*)&Bs[kk][n_base];
            *(float4*)&bb[4] = *(const float4*)&Bs[kk][n_base + 4];
            #pragma unroll
            for (int mi = 0; mi < 8; mi++)
                #pragma unroll
                for (int ni = 0; ni < 8; ni++)
                    acc[mi][ni] = fmaf(a[mi], bb[ni], acc[mi][ni]);
        }
        __syncthreads();
    }

    #pragma unroll
    for (int mi = 0; mi < 8; mi++) {
        int t = t0 + m_base + mi;
        float* o = op + ((size_t)t * 128 + b) * 128 + n_base;
        *(float4*)o       = *(float4*)&acc[mi][0];
        *(float4*)(o + 4) = *(float4*)&acc[mi][4];
    }
}

// ---------- 3. scan + reduce + fill, one dispatch, 512 threads/block ----------
// blocks [0,512)    : scan role, b = id>>2, jq = id&3 (32 columns each). LDS-windowed
//                     producer-consumer, 64-t windows (2 float4 loads/thread/window,
//                     double-buffered); lanes 0..31 run the recurrence, summing
//                     (p0+p1) over the two 256-K chunks.
// blocks [512,1536) : ones-fill for rows with bias > 0.
// blocks [1536,1664): overflow scan (j in [128,count)), only if count > 128.
__global__ __launch_bounds__(512) void scan_fill(const float* __restrict__ xwp,
                                                 const float* __restrict__ xwc1,
                                                 const float* __restrict__ bias,
                                                 float* __restrict__ out) {
    const int T = 512;
    const int id  = blockIdx.x;
    const int tid = threadIdx.x;

    if (id >= 512 && id < 1536) {   // ---- fill ----
        const float4 ones = make_float4(1.f, 1.f, 1.f, 1.f);
        float4* out4 = (float4*)out;
        const size_t base = (size_t)(id - 512) * 8192 + tid;
        #pragma unroll
        for (int q = 0; q < 16; q++) {
            size_t f4 = base + (size_t)q * 512;      // 1024*8192 = 8M float4 = out
            int h = (int)((f4 >> 7) & 511);          // (B,H,T): 128 float4 per h-row
            if (bias[h] > 0.0f) out4[f4] = ones;
        }
        return;
    }

    __shared__ int idx_s[256];
    __shared__ int cnt_s[1];
    __shared__ float4 win[2][64][2][8];   // [buf][t_off][partial][j4]  32 KB
    const int count = block_compact(bias, idx_s, cnt_s);

    if (id >= 1536) {   // ---- overflow scan: j in [128, count), single stream ----
        if (count <= 128) return;
        if (tid >= count - 128) return;
        const int b = id - 1536;
        const int j = 128 + tid;
        const int h = idx_s[j];
        const float bv = bias[h];
        const float* p = xwc1 + (size_t)b * 128 + tid;
        float* o = out + ((size_t)b * 512 + h) * (size_t)T;
        const size_t STR = (size_t)128 * 128;
        float hs = 0.f, y = 0.f;
        float nx[8];
        #pragma unroll
        for (int d = 0; d < 8; d++) nx[d] = p[(size_t)d * STR];
        for (int t0 = 0; t0 < T; t0 += 8) {
            float cur[8], yb[8];
            #pragma unroll
            for (int d = 0; d < 8; d++) cur[d] = nx[d];
            const bool more = (t0 + 8) < T;
            #pragma unroll
            for (int d = 0; d < 8; d++)
                nx[d] = more ? p[(size_t)(t0 + 8 + d) * STR] : 0.f;
            #pragma unroll
            for (int d = 0; d < 8; d++) {
                hs = fmaf(DECAYF * hs, 1.f - y, cur[d]);
                hs = fmaxf(hs, 0.f);
                y  = (hs + bv > 0.f) ? 1.f : 0.f;
                yb[d] = y;
            }
            *(float4*)(o + t0)     = *(float4*)&yb[0];
            *(float4*)(o + t0 + 4) = *(float4*)&yb[4];
        }
        return;
    }

    // ---- main scan: b = id>>2, columns jq*32 .. jq*32+31, 64-t windows ----
    const int b  = id >> 2;
    const int jq = id & 3;
    if (jq * 32 >= count) return;        // uniform per block

    const float4* xwp4 = (const float4*)xwp;
    // load map (x2 per window): tid: j4 = tid&7, p = (tid>>3)&1, t_off = tid>>4 (0..31)
    // and t_off+32.  src float4 = p*PARTF4 + t*4096 + b*32 + jq*8 + j4.
    const int j4l  = tid & 7;
    const int pp   = (tid >> 3) & 1;
    const int toff = tid >> 4;
    const size_t src_base = (size_t)pp * PARTF4 + (size_t)b * 32 + jq * 8 + j4l;

    // compute-lane state (lanes 0..31)
    const int jl = tid;                   // column within quarter
    const int j  = jq * 32 + jl;
    const bool active = (tid < 32) && (j < count);
    const int h = active ? idx_s[j] : 0;
    const float bv = active ? bias[h] : 0.f;
    float* o = out + ((size_t)b * 512 + h) * (size_t)T;
    float hs = 0.f, y = 0.f;

    const float* winf = (const float*)win;

    // prologue: window 0 into buf 0
    {
        win[0][toff     ][pp][j4l] = xwp4[src_base + (size_t)(toff     ) * 4096];
        win[0][toff + 32][pp][j4l] = xwp4[src_base + (size_t)(toff + 32) * 4096];
    }
    __syncthreads();

    for (int w = 0; w < 8; w++) {
        const int buf = w & 1;
        float4 v0, v1;
        const bool more = (w + 1) < 8;
        if (more) {  // issue next window's loads now; consumed at the ds_writes below
            v0 = xwp4[src_base + (size_t)((w + 1) * 64 + toff     ) * 4096];
            v1 = xwp4[src_base + (size_t)((w + 1) * 64 + toff + 32) * 4096];
        }

        if (active) {
            const int t0w = w * 64;
            #pragma unroll
            for (int s = 0; s < 4; s++) {
                float yb[16];
                #pragma unroll
                for (int d = 0; d < 16; d++) {
                    const int rb = ((buf * 64 + s * 16 + d) * 2) * 32 + jl;
                    float sv = winf[rb] + winf[rb + 32];   // (p0+p1)
                    // (1-y) is exactly 0 or 1 -> relu chain matches reference rounding
                    hs = fmaf(DECAYF * hs, 1.f - y, sv);
                    hs = fmaxf(hs, 0.f);
                    y  = (hs + bv > 0.f) ? 1.f : 0.f;
                    yb[d] = y;
                }
                const int t0 = t0w + s * 16;
                *(float4*)(o + t0)      = *(float4*)&yb[0];
                *(float4*)(o + t0 + 4)  = *(float4*)&yb[4];
                *(float4*)(o + t0 + 8)  = *(float4*)&yb[8];
                *(float4*)(o + t0 + 12) = *(float4*)&yb[12];
            }
        }
        if (more) {
            win[buf ^ 1][toff     ][pp][j4l] = v0;   // writes buffer NOT being read
            win[buf ^ 1][toff + 32][pp][j4l] = v1;
        }
        __syncthreads();
    }
}

extern "C" void kernel_launch(void* const* d_in, const int* in_sizes, int n_in,
                              void* d_out, int out_size, void* d_ws, size_t ws_size,
                              hipStream_t stream) {
    const float* x    = (const float*)d_in[0];  // (128, 512, 512)
    const float* W    = (const float*)d_in[1];  // (512, 512)
    const float* bias = (const float*)d_in[2];  // (1, 512)
    float* out = (float*)d_out;                 // (B,H,T) = (128, 512, 512)

    char* ws = (char*)d_ws;
    float* Wc   = (float*)(ws + 4096);
    float* xwp  = (float*)(ws + ((size_t)1 << 20));
    float* xwc1 = (float*)(ws + ((size_t)80 << 20));

    gather_W<<<512, 256, 0, stream>>>(bias, W, Wc);
    dim3 g1(3, 4, 128);   // (2 kc + overflow, t-tiles, B)
    gemm_split<<<g1, 256, 0, stream>>>(x, Wc, bias, xwp, xwc1);
    scan_fill<<<1664, 512, 0, stream>>>(xwp, xwc1, bias, out);
}

// Round 7
// 341.528 us; speedup vs baseline: 1.1354x; 1.0015x over previous
//
#include <hip/hip_runtime.h>

// SNU with bias-sign collapse:
//   y_t = (relu(xw_t + 0.8*h*(1-y)) + b > 0).  relu >= 0, so b_h > 0  =>  y == 1 for all t.
// Only columns with b_h <= 0 (~81 of 512) need the GEMM + sequential scan.
//
// R15:
//   - gemm: verbatim R13 (split-K=4, BK=32, 2048 working blocks). R14 proved block
//     count matters at fixed round structure (1024 blocks: VALU 50%, 134 us; 2048
//     blocks: 58%, 120 us) -- co-resident blocks at different phases fill each
//     other's barrier stalls.
//   - scan: R14's 64-t-window economics on 4 partials via LOADER PRE-SUM: each
//     loader reads its partial pair (p0,p1) or (p2,p3) and writes the pair-sum to
//     LDS; compute lanes add the two pair-sums. (p0+p1)+(p2+p3) association
//     preserved bit-for-bit. 9 barriers (vs 17), 32 KB LDS, half the LDS traffic.
//
// ws layout (bytes):
//   4096    : float Wc[512][256]  gathered W columns (512 KB)
//   1<<20   : float xwp[4][T=512][B=128][128]  4 x 32 MB split-K partials, (t,b,j)
//   129<<20 : float xwc1[T=512][B=128][128]    overflow direct buffer (j in [128,256)),
//                                              touched only if count > 128 (P ~ 6e-9)

#define DECAYF 0.8f
#define PART   ((size_t)512 * 128 * 128)   // floats per split-K partial
#define PARTF4 (PART / 4)                  // float4s per partial

// ---------- per-block compaction recompute: one wave of ballots ----------
__device__ __forceinline__ int block_compact(const float* __restrict__ bias,
                                             int* idx_s, int* cnt_s) {
    const int tid = threadIdx.x;
    if (tid < 64) {
        int base = 0;
        #pragma unroll
        for (int w = 0; w < 8; w++) {
            bool p = bias[w * 64 + tid] <= 0.0f;
            unsigned long long m = __ballot(p);
            if (p) idx_s[base + __popcll(m & ((1ull << tid) - 1ull))] = w * 64 + tid;
            base += __popcll(m);
        }
        if (tid == 0) cnt_s[0] = base;
    }
    __syncthreads();
    const int total = cnt_s[0];
    const int i0 = (total > 0) ? idx_s[0] : 0;
    for (int j = total + tid; j < 256; j += blockDim.x) idx_s[j] = i0;
    __syncthreads();
    return total;
}

// ---------- 1. gather Wc[i][j] = W[i][idx[j]] ----------
__global__ __launch_bounds__(256) void gather_W(const float* __restrict__ bias,
                                                const float* __restrict__ W,
                                                float* __restrict__ Wc) {
    __shared__ int idx_s[256];
    __shared__ int cnt_s[1];
    block_compact(bias, idx_s, cnt_s);
    const int i = blockIdx.x;            // 512 rows
    const int j = threadIdx.x;           // 256 cols
    Wc[i * 256 + j] = W[i * 512 + idx_s[j]];
}

// ---------- 2. GEMM: x(B,I,T) x Wc(I,:) -> partials, split-K=4, BK=32 (R13) ----------
// grid (5, 4, 128) = (kc, t-tiles, B).  kc<4: K-chunk of 128 over cols 0..127
// into xwp[kc] (4 rounds of 32). kc==4: overflow (full K, cols 128..255) -> xwc1;
// exits if count<=128.  FMA order per element identical to R8.
__global__ __launch_bounds__(256) void gemm_split(const float* __restrict__ x,
                                                  const float* __restrict__ Wc,
                                                  const float* __restrict__ bias,
                                                  float* __restrict__ xwp,
                                                  float* __restrict__ xwc1) {
    const int kc = blockIdx.x;
    const int tid = threadIdx.x;
    int kbeg, kend, coff;
    float* op;
    if (kc < 4) { kbeg = kc * 128; kend = kbeg + 128; coff = 0;   op = xwp + (size_t)kc * PART; }
    else {
        __shared__ int cnt_s;
        if (tid < 64) {
            int tot = 0;
            #pragma unroll
            for (int w = 0; w < 8; w++)
                tot += __popcll(__ballot(bias[w * 64 + tid] <= 0.0f));
            if (tid == 0) cnt_s = tot;
        }
        __syncthreads();
        if (cnt_s <= 128) return;
        kbeg = 0; kend = 512; coff = 128; op = xwc1;
    }
    const int I = 512, T = 512, NC = 256;
    const int b  = blockIdx.z;
    const int t0 = blockIdx.y * 128;

    __shared__ float As[32][132];  // [i][t]
    __shared__ float Bs[32][132];  // [i][j]

    const int wave = tid >> 6;
    const int lane = tid & 63;
    const int lx = lane & 7;
    const int ly = lane >> 3;
    const int m_base = ((wave >> 1) << 6) + ly * 8;  // t within tile (0..127)
    const int n_base = ((wave & 1) << 6) + lx * 8;   // j within 128 cols

    float acc[8][8];
    #pragma unroll
    for (int i = 0; i < 8; i++)
        #pragma unroll
        for (int j = 0; j < 8; j++) acc[i][j] = 0.f;

    const float* xb = x + (size_t)b * I * T;

    for (int k0 = kbeg; k0 < kend; k0 += 32) {
        #pragma unroll
        for (int q = 0; q < 4; q++) {   // stage 32x128 of A and B: 4 float4/thread each
            int id2 = tid + q * 256;
            int row = id2 >> 5;             // 0..31
            int c4  = (id2 & 31) << 2;
            *(float4*)&As[row][c4] = *(const float4*)(xb + (size_t)(k0 + row) * T + t0 + c4);
            *(float4*)&Bs[row][c4] = *(const float4*)(Wc + (size_t)(k0 + row) * NC + coff + c4);
        }
        __syncthreads();
        #pragma unroll
        for (int kk = 0; kk < 32; kk++) {
            float a[8], bb[8];
            *(float4*)&a[0]  = *(const float4*)&As[kk][m_base];
            *(float4*)&a[4]  = *(const float4*)&As[kk][m_base + 4];
            *(float4*)&bb[0] = *(const float4*)&Bs[kk][n_base];
            *(float4*)&bb[4] = *(const float4*)&Bs[kk][n_base + 4];
            #pragma unroll
            for (int mi = 0; mi < 8; mi++)
                #pragma unroll
                for (int ni = 0; ni < 8; ni++)
                    acc[mi][ni] = fmaf(a[mi], bb[ni], acc[mi][ni]);
        }
        __syncthreads();
    }

    #pragma unroll
    for (int mi = 0; mi < 8; mi++) {
        int t = t0 + m_base + mi;
        float* o = op + ((size_t)t * 128 + b) * 128 + n_base;
        *(float4*)o       = *(float4*)&acc[mi][0];
        *(float4*)(o + 4) = *(float4*)&acc[mi][4];
    }
}

// ---------- 3. scan + reduce + fill, one dispatch, 512 threads/block ----------
// blocks [0,512)    : scan role, b = id>>2, jq = id&3 (32 columns each). LDS-windowed
//                     producer-consumer, 64-t windows. Each loader reads its partial
//                     PAIR (p0,p1) or (p2,p3) at 2 t-offsets and writes pair-sums to
//                     LDS (4 global loads, 2 ds_writes / thread / window); compute
//                     lanes 0..31 add the two pair-sums: (p0+p1)+(p2+p3) bit-exact.
// blocks [512,1536) : ones-fill for rows with bias > 0.
// blocks [1536,1664): overflow scan (j in [128,count)), only if count > 128.
__global__ __launch_bounds__(512) void scan_fill(const float* __restrict__ xwp,
                                                 const float* __restrict__ xwc1,
                                                 const float* __restrict__ bias,
                                                 float* __restrict__ out) {
    const int T = 512;
    const int id  = blockIdx.x;
    const int tid = threadIdx.x;

    if (id >= 512 && id < 1536) {   // ---- fill ----
        const float4 ones = make_float4(1.f, 1.f, 1.f, 1.f);
        float4* out4 = (float4*)out;
        const size_t base = (size_t)(id - 512) * 8192 + tid;
        #pragma unroll
        for (int q = 0; q < 16; q++) {
            size_t f4 = base + (size_t)q * 512;      // 1024*8192 = 8M float4 = out
            int h = (int)((f4 >> 7) & 511);          // (B,H,T): 128 float4 per h-row
            if (bias[h] > 0.0f) out4[f4] = ones;
        }
        return;
    }

    __shared__ int idx_s[256];
    __shared__ int cnt_s[1];
    __shared__ float4 win[2][64][2][8];   // [buf][t_off][pair][j4]  32 KB
    const int count = block_compact(bias, idx_s, cnt_s);

    if (id >= 1536) {   // ---- overflow scan: j in [128, count), single stream ----
        if (count <= 128) return;
        if (tid >= count - 128) return;
        const int b = id - 1536;
        const int j = 128 + tid;
        const int h = idx_s[j];
        const float bv = bias[h];
        const float* p = xwc1 + (size_t)b * 128 + tid;
        float* o = out + ((size_t)b * 512 + h) * (size_t)T;
        const size_t STR = (size_t)128 * 128;
        float hs = 0.f, y = 0.f;
        float nx[8];
        #pragma unroll
        for (int d = 0; d < 8; d++) nx[d] = p[(size_t)d * STR];
        for (int t0 = 0; t0 < T; t0 += 8) {
            float cur[8], yb[8];
            #pragma unroll
            for (int d = 0; d < 8; d++) cur[d] = nx[d];
            const bool more = (t0 + 8) < T;
            #pragma unroll
            for (int d = 0; d < 8; d++)
                nx[d] = more ? p[(size_t)(t0 + 8 + d) * STR] : 0.f;
            #pragma unroll
            for (int d = 0; d < 8; d++) {
                hs = fmaf(DECAYF * hs, 1.f - y, cur[d]);
                hs = fmaxf(hs, 0.f);
                y  = (hs + bv > 0.f) ? 1.f : 0.f;
                yb[d] = y;
            }
            *(float4*)(o + t0)     = *(float4*)&yb[0];
            *(float4*)(o + t0 + 4) = *(float4*)&yb[4];
        }
        return;
    }

    // ---- main scan: b = id>>2, columns jq*32 .. jq*32+31, 64-t windows ----
    const int b  = id >> 2;
    const int jq = id & 3;
    if (jq * 32 >= count) return;        // uniform per block

    const float4* xwp4 = (const float4*)xwp;
    // loader map: tid -> j4 = tid&7, pr = (tid>>3)&1 (partials 2pr, 2pr+1),
    // toff = tid>>4 (0..31; covers t_off and t_off+32).
    //   src float4 = p*PARTF4 + t*4096 + b*32 + jq*8 + j4, t = w*64 + t_off
    const int j4l  = tid & 7;
    const int pr   = (tid >> 3) & 1;
    const int toff = tid >> 4;
    const size_t pa = (size_t)(2 * pr)     * PARTF4 + (size_t)b * 32 + jq * 8 + j4l;
    const size_t pb = (size_t)(2 * pr + 1) * PARTF4 + (size_t)b * 32 + jq * 8 + j4l;

    // compute-lane state (lanes 0..31)
    const int jl = tid;                   // column within quarter
    const int j  = jq * 32 + jl;
    const bool active = (tid < 32) && (j < count);
    const int h = active ? idx_s[j] : 0;
    const float bv = active ? bias[h] : 0.f;
    float* o = out + ((size_t)b * 512 + h) * (size_t)T;
    float hs = 0.f, y = 0.f;

    const float* winf = (const float*)win;

    #define PSUM(u, v) make_float4((u).x + (v).x, (u).y + (v).y, (u).z + (v).z, (u).w + (v).w)

    // prologue: window 0 into buf 0 (pair-sums)
    {
        float4 a0 = xwp4[pa + (size_t)(toff     ) * 4096];
        float4 b0 = xwp4[pb + (size_t)(toff     ) * 4096];
        float4 a1 = xwp4[pa + (size_t)(toff + 32) * 4096];
        float4 b1 = xwp4[pb + (size_t)(toff + 32) * 4096];
        win[0][toff     ][pr][j4l] = PSUM(a0, b0);
        win[0][toff + 32][pr][j4l] = PSUM(a1, b1);
    }
    __syncthreads();

    for (int w = 0; w < 8; w++) {
        const int buf = w & 1;
        float4 a0, b0, a1, b1;
        const bool more = (w + 1) < 8;
        if (more) {  // issue next window's loads now; consumed at the ds_writes below
            a0 = xwp4[pa + (size_t)((w + 1) * 64 + toff     ) * 4096];
            b0 = xwp4[pb + (size_t)((w + 1) * 64 + toff     ) * 4096];
            a1 = xwp4[pa + (size_t)((w + 1) * 64 + toff + 32) * 4096];
            b1 = xwp4[pb + (size_t)((w + 1) * 64 + toff + 32) * 4096];
        }

        if (active) {
            const int t0w = w * 64;
            #pragma unroll
            for (int s = 0; s < 4; s++) {
                float yb[16];
                #pragma unroll
                for (int d = 0; d < 16; d++) {
                    const int td = s * 16 + d;
                    const int rb = (buf * 128 + td * 2) * 32 + jl;
                    float sv = winf[rb] + winf[rb + 32];   // (p0+p1) + (p2+p3)
                    // (1-y) is exactly 0 or 1 -> relu chain matches reference rounding
                    hs = fmaf(DECAYF * hs, 1.f - y, sv);
                    hs = fmaxf(hs, 0.f);
                    y  = (hs + bv > 0.f) ? 1.f : 0.f;
                    yb[d] = y;
                }
                const int t0 = t0w + s * 16;
                *(float4*)(o + t0)      = *(float4*)&yb[0];
                *(float4*)(o + t0 + 4)  = *(float4*)&yb[4];
                *(float4*)(o + t0 + 8)  = *(float4*)&yb[8];
                *(float4*)(o + t0 + 12) = *(float4*)&yb[12];
            }
        }
        if (more) {
            win[buf ^ 1][toff     ][pr][j4l] = PSUM(a0, b0);   // buffer NOT being read
            win[buf ^ 1][toff + 32][pr][j4l] = PSUM(a1, b1);
        }
        __syncthreads();
    }
    #undef PSUM
}

extern "C" void kernel_launch(void* const* d_in, const int* in_sizes, int n_in,
                              void* d_out, int out_size, void* d_ws, size_t ws_size,
                              hipStream_t stream) {
    const float* x    = (const float*)d_in[0];  // (128, 512, 512)
    const float* W    = (const float*)d_in[1];  // (512, 512)
    const float* bias = (const float*)d_in[2];  // (1, 512)
    float* out = (float*)d_out;                 // (B,H,T) = (128, 512, 512)

    char* ws = (char*)d_ws;
    float* Wc   = (float*)(ws + 4096);
    float* xwp  = (float*)(ws + ((size_t)1 << 20));
    float* xwc1 = (float*)(ws + ((size_t)129 << 20));

    gather_W<<<512, 256, 0, stream>>>(bias, W, Wc);
    dim3 g1(5, 4, 128);   // (4 kc + overflow, t-tiles, B)
    gemm_split<<<g1, 256, 0, stream>>>(x, Wc, bias, xwp, xwc1);
    scan_fill<<<1664, 512, 0, stream>>>(xwp, xwc1, bias, out);
}